// Round 1
// baseline (345.465 us; speedup 1.0000x reference)
//
#include <hip/hip_runtime.h>
#include <cstddef>
#include <cstdint>

#define N_NODES 50000
#define N_EDGES 800000
#define IN_CH 128
#define HID 64
#define OUT_CH 32

// ---------------- edge decode (int32 vs int64 decided at runtime) ----------
__device__ __forceinline__ void load_edge(const void* ei, int flag, int e, int& s, int& d) {
    if (flag) {  // int64 data
        const long long* p = (const long long*)ei;
        s = (int)p[e];
        d = (int)p[e + N_EDGES];
    } else {     // int32 data
        const int* p = (const int*)ei;
        s = p[e];
        d = p[e + N_EDGES];
    }
}

// flag=1 iff data is int64: odd int32 words (high halves) are all zero.
__global__ __launch_bounds__(256) void detect_kernel(const unsigned* ei, int* flagp) {
    __shared__ unsigned red[256];
    unsigned acc = 0;
    for (int i = threadIdx.x; i < 2048; i += 256) acc |= ei[2 * i + 1];
    red[threadIdx.x] = acc;
    __syncthreads();
    if (threadIdx.x == 0) {
        unsigned o = 0;
        for (int i = 0; i < 256; ++i) o |= red[i];
        *flagp = (o == 0) ? 1 : 0;
    }
}

__global__ __launch_bounds__(256) void deg_kernel(const void* ei, const int* flagp, int* deg) {
    const int flag = *flagp;
    int e = blockIdx.x * 256 + threadIdx.x;
    if (e < N_EDGES) {
        int s, d;
        load_edge(ei, flag, e, s, d);
        atomicAdd(&deg[d], 1);
    }
}

__global__ __launch_bounds__(256) void dis_kernel(const int* deg, float* dis) {
    int i = blockIdx.x * 256 + threadIdx.x;
    if (i < N_NODES) dis[i] = rsqrtf((float)deg[i] + 1.0f);
}

// --------------- GEMM1: h1 = x @ W1 ; agg1 = h1*dis^2 + b1 -----------------
// tile: 64 rows x 64 cols, K=128. block 256 threads, 4x4 register tile/thread.
__global__ __launch_bounds__(256) void gemm1_kernel(
        const float* __restrict__ x, const float* __restrict__ W1,
        const float* __restrict__ b1, const float* __restrict__ dis,
        float* __restrict__ h1, float* __restrict__ agg1) {
    extern __shared__ float smem[];
    float (*xs)[132] = (float(*)[132])smem;            // 64 x 132
    float (*wsh)[68] = (float(*)[68])(smem + 64 * 132); // 128 x 68

    const int t = threadIdx.x;
    const int brow = blockIdx.x * 64;

    // stage W1 (128x64) as float4
    for (int f = t; f < 2048; f += 256) {
        int r = f >> 4, c = (f & 15) << 2;
        float4 v = ((const float4*)W1)[f];
        *(float4*)&wsh[r][c] = v;
    }
    // stage x tile (64x128)
    for (int f = t; f < 2048; f += 256) {
        int r = f >> 5, c = (f & 31) << 2;
        int gr = brow + r;
        float4 v = make_float4(0.f, 0.f, 0.f, 0.f);
        if (gr < N_NODES) v = *(const float4*)(x + gr * IN_CH + c);
        *(float4*)&xs[r][c] = v;
    }
    __syncthreads();

    const int tc = (t & 15) << 2;  // 4 cols
    const int tr = (t >> 4) << 2;  // 4 rows
    float acc[4][4] = {};
#pragma unroll 4
    for (int k4 = 0; k4 < 32; ++k4) {
        const int k = k4 << 2;
        float xr[4][4], wr[4][4];
#pragma unroll
        for (int i = 0; i < 4; ++i) {
            float4 v = *(const float4*)&xs[tr + i][k];
            xr[i][0] = v.x; xr[i][1] = v.y; xr[i][2] = v.z; xr[i][3] = v.w;
        }
#pragma unroll
        for (int j = 0; j < 4; ++j) {
            float4 v = *(const float4*)&wsh[k + j][tc];
            wr[j][0] = v.x; wr[j][1] = v.y; wr[j][2] = v.z; wr[j][3] = v.w;
        }
#pragma unroll
        for (int i = 0; i < 4; ++i)
#pragma unroll
            for (int c = 0; c < 4; ++c)
                acc[i][c] += xr[i][0] * wr[0][c] + xr[i][1] * wr[1][c]
                           + xr[i][2] * wr[2][c] + xr[i][3] * wr[3][c];
    }

#pragma unroll
    for (int i = 0; i < 4; ++i) {
        int r = brow + tr + i;
        if (r < N_NODES) {
            float ds = dis[r];
            float d2 = ds * ds;
            float4 hv = make_float4(acc[i][0], acc[i][1], acc[i][2], acc[i][3]);
            *(float4*)(h1 + r * HID + tc) = hv;
            float4 av = make_float4(hv.x * d2 + b1[tc + 0], hv.y * d2 + b1[tc + 1],
                                    hv.z * d2 + b1[tc + 2], hv.w * d2 + b1[tc + 3]);
            *(float4*)(agg1 + r * HID + tc) = av;
        }
    }
}

// --------------- scatter1: agg1[dst] += h1[src] * norm ---------------------
__global__ __launch_bounds__(256) void scatter1_kernel(
        const void* ei, const int* flagp, const float* __restrict__ dis,
        const float* __restrict__ h1, float* __restrict__ agg1) {
    const int flag = *flagp;
    const int lane = threadIdx.x & 63;
    int wid = blockIdx.x * 4 + (threadIdx.x >> 6);
    const int nw = gridDim.x * 4;
    for (int e = wid; e < N_EDGES; e += nw) {
        int s, d;
        load_edge(ei, flag, e, s, d);
        float norm = dis[s] * dis[d];
        float v = h1[s * HID + lane] * norm;
        atomicAdd(&agg1[d * HID + lane], v);
    }
}

// --------------- GEMM2: h2 = relu(agg1) @ W2 ; out = h2*dis^2 + b2 ---------
// tile: 128 rows x 32 cols, K=64. block 256, 4x4 register tile/thread.
__global__ __launch_bounds__(256) void gemm2_kernel(
        const float* __restrict__ agg1, const float* __restrict__ W2,
        const float* __restrict__ b2, const float* __restrict__ dis,
        float* __restrict__ h2, float* __restrict__ out) {
    extern __shared__ float smem[];
    float (*xs)[68] = (float(*)[68])smem;               // 128 x 68
    float (*wsh)[36] = (float(*)[36])(smem + 128 * 68); // 64 x 36

    const int t = threadIdx.x;
    const int brow = blockIdx.x * 128;

    // stage W2 (64x32)
    for (int f = t; f < 512; f += 256) {
        int r = f >> 3, c = (f & 7) << 2;
        float4 v = ((const float4*)W2)[f];
        *(float4*)&wsh[r][c] = v;
    }
    // stage relu(agg1) tile (128x64)
    for (int f = t; f < 2048; f += 256) {
        int r = f >> 4, c = (f & 15) << 2;
        int gr = brow + r;
        float4 v = make_float4(0.f, 0.f, 0.f, 0.f);
        if (gr < N_NODES) {
            v = *(const float4*)(agg1 + gr * HID + c);
            v.x = fmaxf(v.x, 0.f); v.y = fmaxf(v.y, 0.f);
            v.z = fmaxf(v.z, 0.f); v.w = fmaxf(v.w, 0.f);
        }
        *(float4*)&xs[r][c] = v;
    }
    __syncthreads();

    const int tc = (t & 7) << 2;   // 4 cols of 32
    const int tr = (t >> 3) << 2;  // 4 rows of 128
    float acc[4][4] = {};
#pragma unroll 4
    for (int k4 = 0; k4 < 16; ++k4) {
        const int k = k4 << 2;
        float xr[4][4], wr[4][4];
#pragma unroll
        for (int i = 0; i < 4; ++i) {
            float4 v = *(const float4*)&xs[tr + i][k];
            xr[i][0] = v.x; xr[i][1] = v.y; xr[i][2] = v.z; xr[i][3] = v.w;
        }
#pragma unroll
        for (int j = 0; j < 4; ++j) {
            float4 v = *(const float4*)&wsh[k + j][tc];
            wr[j][0] = v.x; wr[j][1] = v.y; wr[j][2] = v.z; wr[j][3] = v.w;
        }
#pragma unroll
        for (int i = 0; i < 4; ++i)
#pragma unroll
            for (int c = 0; c < 4; ++c)
                acc[i][c] += xr[i][0] * wr[0][c] + xr[i][1] * wr[1][c]
                           + xr[i][2] * wr[2][c] + xr[i][3] * wr[3][c];
    }

#pragma unroll
    for (int i = 0; i < 4; ++i) {
        int r = brow + tr + i;
        if (r < N_NODES) {
            float ds = dis[r];
            float d2 = ds * ds;
            float4 hv = make_float4(acc[i][0], acc[i][1], acc[i][2], acc[i][3]);
            *(float4*)(h2 + r * OUT_CH + tc) = hv;
            float4 ov = make_float4(hv.x * d2 + b2[tc + 0], hv.y * d2 + b2[tc + 1],
                                    hv.z * d2 + b2[tc + 2], hv.w * d2 + b2[tc + 3]);
            *(float4*)(out + r * OUT_CH + tc) = ov;
        }
    }
}

// --------------- scatter2: out[dst] += h2[src] * norm ----------------------
__global__ __launch_bounds__(256) void scatter2_kernel(
        const void* ei, const int* flagp, const float* __restrict__ dis,
        const float* __restrict__ h2, float* __restrict__ out) {
    const int flag = *flagp;
    const int lane = threadIdx.x & 63;
    const int half = lane >> 5;   // 2 edges per wave
    const int c = lane & 31;
    int wid = blockIdx.x * 4 + (threadIdx.x >> 6);
    const int nw = gridDim.x * 4;
    for (int e0 = wid * 2; e0 < N_EDGES; e0 += nw * 2) {
        int e = e0 + half;  // N_EDGES is even -> always valid
        int s, d;
        load_edge(ei, flag, e, s, d);
        float norm = dis[s] * dis[d];
        float v = h2[s * OUT_CH + c] * norm;
        atomicAdd(&out[d * OUT_CH + c], v);
    }
}

extern "C" void kernel_launch(void* const* d_in, const int* in_sizes, int n_in,
                              void* d_out, int out_size, void* d_ws, size_t ws_size,
                              hipStream_t stream) {
    const float* x  = (const float*)d_in[0];
    const float* W1 = (const float*)d_in[1];
    const float* b1 = (const float*)d_in[2];
    const float* W2 = (const float*)d_in[3];
    const float* b2 = (const float*)d_in[4];
    const void*  ei = d_in[5];
    float* out = (float*)d_out;

    char* ws = (char*)d_ws;
    int*   flagp = (int*)ws;                                   // 512 B
    int*   deg   = (int*)(ws + 512);                           // 200704 B
    float* dis   = (float*)(ws + 512 + 200704);                // 200704 B
    float* h1    = (float*)(ws + 512 + 2 * 200704);            // 12.8 MB
    float* agg1  = h1 + (size_t)N_NODES * HID;                 // 12.8 MB
    float* h2    = agg1 + (size_t)N_NODES * HID;               // 6.4 MB

    hipMemsetAsync(deg, 0, N_NODES * sizeof(int), stream);
    detect_kernel<<<1, 256, 0, stream>>>((const unsigned*)ei, flagp);
    deg_kernel<<<(N_EDGES + 255) / 256, 256, 0, stream>>>(ei, flagp, deg);
    dis_kernel<<<(N_NODES + 255) / 256, 256, 0, stream>>>(deg, dis);

    size_t sh1 = (64 * 132 + 128 * 68) * sizeof(float);
    gemm1_kernel<<<(N_NODES + 63) / 64, 256, sh1, stream>>>(x, W1, b1, dis, h1, agg1);

    scatter1_kernel<<<2048, 256, 0, stream>>>(ei, flagp, dis, h1, agg1);

    size_t sh2 = (128 * 68 + 64 * 36) * sizeof(float);
    gemm2_kernel<<<(N_NODES + 127) / 128, 256, sh2, stream>>>(agg1, W2, b2, dis, h2, out);

    scatter2_kernel<<<2048, 256, 0, stream>>>(ei, flagp, dis, h2, out);
}